// Round 11
// baseline (254075.464 us; speedup 1.0000x reference)
//
#include <hip/hip_runtime.h>

#define IDIM  64
#define HDIM  512
#define T_LEN 65536
#define NWG   128
#define NTHR  576   // 1 poller wave + 8 compute waves

// Merged tagged hidden state, parity-aligned: g_hh[p][0..511] = h1 parity p,
// g_hh[p][512..1023] = h2 (parity-flipped storage so consumers read ONE buffer).
// Record: high 32 = tick tag, low 32 = float payload. Tag check = barrier.
// Producers at tick k (both layers) write g_hh[k&1]; consumers read g_hh[(k+1)&1].
__device__ unsigned long long g_hh[2][2 * HDIM];

__device__ __forceinline__ unsigned long long pack(float v, int k) {
  return ((unsigned long long)(unsigned)k << 32) | (unsigned long long)__float_as_uint(v);
}

__global__ void lstm_init() {
  int t = threadIdx.x;
  for (int e = t; e < HDIM; e += blockDim.x) {
    g_hh[1][e]        = 0xFFFFFFFF00000000ull; // h1 tag=-1 val=0 : read at tick 0
    g_hh[0][e]        = 0xFFFFFFFE00000000ull; // h1 never-match : overwritten at tick 0
    g_hh[1][HDIM + e] = 0xFFFFFFFF00000000ull; // h2 tag=-1 val=0 : read at tick 0
    g_hh[0][HDIM + e] = 0x0000000000000000ull; // h2 tag=0 val=0 : h2(-1), read at tick 1
  }
}

__global__ __launch_bounds__(NTHR)
__attribute__((amdgpu_waves_per_eu(3, 3)))   // 9 waves/block -> 3/EU; 170-VGPR budget keeps w[64] resident
void lstm_main(
    const float* __restrict__ x_seq,
    const float* __restrict__ W_ih1, const float* __restrict__ W_hh1,
    const float* __restrict__ b_ih1, const float* __restrict__ b_hh1,
    const float* __restrict__ W_ih2, const float* __restrict__ W_hh2,
    const float* __restrict__ b_ih2, const float* __restrict__ b_hh2,
    const float* __restrict__ W_out, const float* __restrict__ b_out,
    float* __restrict__ out)
{
  const int wg   = blockIdx.x;
  const int tid  = threadIdx.x;
  const int wave = tid >> 6;      // 0 = poller, 1..8 = compute
  const int lane = tid & 63;

  __shared__ __align__(16) float vec[2][HDIM + IDIM + HDIM]; // [h1 | x | h2] x2

  if (wave == 0) {
    // ================= POLLER WAVE =================
    // Lane L scans slots {L + 64*i}, i=0..15: 16 independent agent-scope loads
    // stay in flight together (counted vmcnt) -> ~1 RTT per iteration; polls
    // tick k+1 while compute waves run tick k (overlap).
    int bud = 1 << 24;   // fail fast (wrong), never hang
    for (int k = 0; k <= T_LEN; ++k) {
      const unsigned expect = (unsigned)(k - 1);
      const int pb  = (k + 1) & 1;
      const int buf = k & 1;
      float xv = 0.f;
      if (k < T_LEN) xv = x_seq[(size_t)k * IDIM + lane];

      unsigned long long v[16];
      bool allok;
      do {
#pragma unroll
        for (int i = 0; i < 16; ++i)
          v[i] = __hip_atomic_load(&g_hh[pb][lane + 64 * i],
                                   __ATOMIC_RELAXED, __HIP_MEMORY_SCOPE_AGENT);
        bool ok = true;
#pragma unroll
        for (int i = 0; i < 16; ++i) ok &= ((unsigned)(v[i] >> 32) == expect);
        allok = __all(ok);
      } while (!allok && --bud > 0);

#pragma unroll
      for (int i = 0; i < 16; ++i) {
        const int slot = lane + 64 * i;
        const int dst  = (slot < HDIM) ? slot : slot + IDIM;  // skip x gap for h2
        vec[buf][dst] = __uint_as_float((unsigned)v[i]);
      }
      vec[buf][HDIM + lane] = xv;
      __syncthreads();   // fill k complete; compute waves proceed, poller moves to k+1
    }

    // ---- final output: out = W_out . h2(T-1) + b_out (tag T_LEN, parity 0) ----
    if (wg == 0) {
      float acc = 0.f;
      int bud2 = 1 << 24;
#pragma unroll
      for (int e = 0; e < HDIM / 64; ++e) {
        const int idx = lane + e * 64;
        unsigned long long u;
        do {
          u = __hip_atomic_load(&g_hh[0][HDIM + idx],
                                __ATOMIC_RELAXED, __HIP_MEMORY_SCOPE_AGENT);
        } while ((unsigned)(u >> 32) != (unsigned)T_LEN && --bud2 > 0);
        acc = fmaf(W_out[idx], __uint_as_float((unsigned)u), acc);
      }
      acc += __shfl_xor(acc, 32, 64);
      acc += __shfl_xor(acc, 16, 64);
      acc += __shfl_xor(acc, 8, 64);
      acc += __shfl_xor(acc, 4, 64);
      acc += __shfl_xor(acc, 2, 64);
      acc += __shfl_xor(acc, 1, 64);
      if (lane == 0) out[0] = acc + b_out[0];
    }
    return;
  }

  // ================= COMPUTE WAVES (R5 structure, unchanged math) =================
  const int cw   = wave - 1;      // 0..7
  const int role = cw >> 2;       // 0 = layer1, 1 = layer2
  const int g    = lane >> 4;     // gate 0..3 (i,f,g,o)
  const int s    = lane & 15;     // strip 0..15
  const int j    = wg * 4 + (cw & 3);     // owned hidden index
  const int r    = g * HDIM + j;          // gate row in [0,2048)

  float w[64];
  if (role == 0) {
    // layer1 row = [W_hh1[r,0:512] | W_ih1[r,0:64]]; lane covers e = s*36 .. s*36+35
#pragma unroll
    for (int m = 0; m < 36; ++m) {
      int e = s * 36 + m;
      w[m] = (e < HDIM) ? W_hh1[(size_t)r * HDIM + e]
                        : W_ih1[(size_t)r * IDIM + (e - HDIM)];
    }
#pragma unroll
    for (int m = 0; m < 36; ++m) asm volatile("" : "+v"(w[m]));
  } else {
    // layer2 row = [W_ih2[r,0:512] | W_hh2[r,0:512]]; chunk-rotated by s
#pragma unroll
    for (int c = 0; c < 16; ++c) {
#pragma unroll
      for (int i = 0; i < 4; ++i) {
        int er = s * 64 + ((c + s) & 15) * 4 + i;   // 0..1023
        w[c * 4 + i] = (er < HDIM) ? W_ih2[(size_t)r * HDIM + er]
                                   : W_hh2[(size_t)r * HDIM + (er - HDIM)];
      }
    }
#pragma unroll
    for (int m = 0; m < 64; ++m) asm volatile("" : "+v"(w[m]));
  }
  const float bsel = (role == 0) ? (b_ih1[r] + b_hh1[r]) : (b_ih2[r] + b_hh2[r]);

  float cst = 0.f;

  for (int k = 0; k <= T_LEN; ++k) {
    const int buf = k & 1;
    __syncthreads();   // wait for poller's fill of tick k

    const bool active = (role == 0) ? (k < T_LEN) : (k > 0);
    if (active) {
      float acc = 0.f;
      if (role == 0) {
#pragma unroll
        for (int mc = 0; mc < 9; ++mc) {
          const float4 hv = *reinterpret_cast<const float4*>(&vec[buf][s * 36 + mc * 4]);
          acc = fmaf(w[mc * 4 + 0], hv.x, acc);
          acc = fmaf(w[mc * 4 + 1], hv.y, acc);
          acc = fmaf(w[mc * 4 + 2], hv.z, acc);
          acc = fmaf(w[mc * 4 + 3], hv.w, acc);
        }
      } else {
        const int vb = (s < 8) ? 0 : IDIM;  // skip the x gap for the h2 half
#pragma unroll
        for (int c = 0; c < 16; ++c) {
          const int off = s * 64 + ((c + s) & 15) * 4 + vb;
          const float4 hv = *reinterpret_cast<const float4*>(&vec[buf][off]);
          acc = fmaf(w[c * 4 + 0], hv.x, acc);
          acc = fmaf(w[c * 4 + 1], hv.y, acc);
          acc = fmaf(w[c * 4 + 2], hv.z, acc);
          acc = fmaf(w[c * 4 + 3], hv.w, acc);
        }
      }
      acc += __shfl_xor(acc, 8, 16);
      acc += __shfl_xor(acc, 4, 16);
      acc += __shfl_xor(acc, 2, 16);
      acc += __shfl_xor(acc, 1, 16);

      // per-group activation (tanh via 2*sigmoid(2x)-1), broadcast activated gates
      const float xs  = acc + bsel;
      const float xin = (g == 2) ? 2.f * xs : xs;
      const float sgm = 1.f / (1.f + expf(-xin));
      const float act = (g == 2) ? 2.f * sgm - 1.f : sgm;
      const float ai = __shfl(act, 0, 64);
      const float af = __shfl(act, 16, 64);
      const float ag = __shfl(act, 32, 64);
      const float ao = __shfl(act, 48, 64);
      cst = af * cst + ai * ag;
      const float tc = 2.f / (1.f + expf(-2.f * cst)) - 1.f;   // tanh(cst)
      const float hv = ao * tc;
      if (lane == 0) {
        const int vidx = (role == 0) ? j : (HDIM + j);
        __hip_atomic_store(&g_hh[k & 1][vidx], pack(hv, k),
                           __ATOMIC_RELAXED, __HIP_MEMORY_SCOPE_AGENT);
      }
    }
    // no trailing barrier: double-buffered vec; poller's next fill targets buf^1
  }
}

extern "C" void kernel_launch(void* const* d_in, const int* in_sizes, int n_in,
                              void* d_out, int out_size, void* d_ws, size_t ws_size,
                              hipStream_t stream) {
  const float* x_seq = (const float*)d_in[0];
  const float* W_ih1 = (const float*)d_in[1];
  const float* W_hh1 = (const float*)d_in[2];
  const float* b_ih1 = (const float*)d_in[3];
  const float* b_hh1 = (const float*)d_in[4];
  const float* W_ih2 = (const float*)d_in[5];
  const float* W_hh2 = (const float*)d_in[6];
  const float* b_ih2 = (const float*)d_in[7];
  const float* b_hh2 = (const float*)d_in[8];
  const float* W_out = (const float*)d_in[9];
  const float* b_out = (const float*)d_in[10];
  float* out = (float*)d_out;

  hipLaunchKernelGGL(lstm_init, dim3(1), dim3(256), 0, stream);
  hipLaunchKernelGGL(lstm_main, dim3(NWG), dim3(NTHR), 0, stream,
                     x_seq, W_ih1, W_hh1, b_ih1, b_hh1,
                     W_ih2, W_hh2, b_ih2, b_hh2, W_out, b_out, out);
}

// Round 12
// 182978.882 us; speedup vs baseline: 1.3886x; 1.3886x over previous
//
#include <hip/hip_runtime.h>

#define IDIM  64
#define HDIM  512
#define T_LEN 65536
#define NWG   128
#define NTHR  512
#define RD    4     // h1 ring depth

// h1 ring: tag k lives at slot k%RD (tagged 8B records: hi32=tag, lo32=float).
// h2 parity ring: tag m at m&1. prog[w2]=m certifies L2 WG w2 has loaded h1(m).
__device__ unsigned long long g_r1[RD][HDIM];
__device__ unsigned long long g_r2[2][HDIM];
__device__ long long g_prog[64];

__device__ __forceinline__ unsigned long long pack(float v, int k) {
  return ((unsigned long long)(unsigned)k << 32) | (unsigned long long)__float_as_uint(v);
}

__global__ void lstm_init() {
  int t = threadIdx.x;
  for (int e = t; e < HDIM; e += blockDim.x) {
    g_r1[RD - 1][e] = 0xFFFFFFFF00000000ull;  // h1(-1): tag=-1 val=0, read by L1 tick 0
    for (int d = 0; d < RD - 1; ++d) g_r1[d][e] = 0xFFFFFFFE00000000ull; // never-match
    g_r2[1][e] = 0xFFFFFFFF00000000ull;       // h2(-1): tag=-1 val=0, read by L2 step 0
    g_r2[0][e] = 0xFFFFFFFE00000000ull;       // never-match until step 0 writes
  }
  if (t < 64) g_prog[t] = -1;
}

__global__ __launch_bounds__(NTHR)
__attribute__((amdgpu_waves_per_eu(2, 2)))   // the ONLY shape that keeps w[] resident (VGPR 88)
void lstm_main(
    const float* __restrict__ x_seq,
    const float* __restrict__ W_ih1, const float* __restrict__ W_hh1,
    const float* __restrict__ b_ih1, const float* __restrict__ b_hh1,
    const float* __restrict__ W_ih2, const float* __restrict__ W_hh2,
    const float* __restrict__ b_ih2, const float* __restrict__ b_hh2,
    const float* __restrict__ W_out, const float* __restrict__ b_out,
    float* __restrict__ out)
{
  const int wg   = blockIdx.x;
  const int tid  = threadIdx.x;
  const int wave = tid >> 6;      // 0..7
  const int lane = tid & 63;
  const int g    = lane >> 4;     // gate 0..3 (i,f,g,o)
  const int s    = lane & 15;     // strip 0..15

  __shared__ __align__(16) float vec[2][2 * HDIM];  // L1 uses [..][0..575], L2 uses [..][0..1023]
  int bud = 1 << 24;              // global spin budget: fail fast (wrong), never hang

  if (wg < 64) {
    // ================= LAYER-1 DOMAIN (WGs 0..63) =================
    const int j = wg * 8 + wave;          // owned h1 index
    const int r = g * HDIM + j;
    float wa[36];                          // row = [W_hh1[r,0:512] | W_ih1[r,0:64]]
#pragma unroll
    for (int m = 0; m < 36; ++m) {
      int e = s * 36 + m;
      wa[m] = (e < HDIM) ? W_hh1[(size_t)r * HDIM + e]
                         : W_ih1[(size_t)r * IDIM + (e - HDIM)];
    }
#pragma unroll
    for (int m = 0; m < 36; ++m) asm volatile("" : "+v"(wa[m]));
    const float bsel = b_ih1[r] + b_hh1[r];
    float cst = 0.f;

    for (int k = 0; k < T_LEN; ++k) {
      const int buf = k & 1;
      const unsigned expect = (unsigned)(k - 1);
      const long long kd = (long long)k - RD;

      float xv = 0.f;
      if (tid < IDIM) xv = x_seq[(size_t)k * IDIM + tid];

      // poll h1(k-1) [own domain] + L2 progress >= k-RD (ring back-pressure)
      unsigned long long a = 0;
      bool ok1 = false, okp = (tid >= 64);
      do {
        if (!ok1) {
          a = __hip_atomic_load(&g_r1[(k + RD - 1) % RD][tid],
                                __ATOMIC_RELAXED, __HIP_MEMORY_SCOPE_AGENT);
          ok1 = ((unsigned)(a >> 32) == expect);
        }
        if (!okp) {
          long long p = __hip_atomic_load(&g_prog[tid],
                                          __ATOMIC_RELAXED, __HIP_MEMORY_SCOPE_AGENT);
          okp = (p >= kd);
        }
      } while ((!ok1 || !okp) && --bud > 0);

      vec[buf][tid] = __uint_as_float((unsigned)a);
      if (tid < IDIM) vec[buf][HDIM + tid] = xv;
      __syncthreads();   // one barrier/tick; vec double-buffered

      float acc = 0.f;
#pragma unroll
      for (int mc = 0; mc < 9; ++mc) {
        const float4 hv = *reinterpret_cast<const float4*>(&vec[buf][s * 36 + mc * 4]);
        acc = fmaf(wa[mc * 4 + 0], hv.x, acc);
        acc = fmaf(wa[mc * 4 + 1], hv.y, acc);
        acc = fmaf(wa[mc * 4 + 2], hv.z, acc);
        acc = fmaf(wa[mc * 4 + 3], hv.w, acc);
      }
      acc += __shfl_xor(acc, 8, 16);
      acc += __shfl_xor(acc, 4, 16);
      acc += __shfl_xor(acc, 2, 16);
      acc += __shfl_xor(acc, 1, 16);
      const float xs  = acc + bsel;
      const float xin = (g == 2) ? 2.f * xs : xs;
      const float sgm = 1.f / (1.f + expf(-xin));
      const float act = (g == 2) ? 2.f * sgm - 1.f : sgm;
      const float ai = __shfl(act, 0, 64);
      const float af = __shfl(act, 16, 64);
      const float ag = __shfl(act, 32, 64);
      const float ao = __shfl(act, 48, 64);
      cst = af * cst + ai * ag;
      const float tc = 2.f / (1.f + expf(-2.f * cst)) - 1.f;   // tanh
      const float hv1 = ao * tc;
      if (lane == 0)
        __hip_atomic_store(&g_r1[k % RD][j], pack(hv1, k),
                           __ATOMIC_RELAXED, __HIP_MEMORY_SCOPE_AGENT);
    }
  } else {
    // ================= LAYER-2 DOMAIN (WGs 64..127) =================
    const int w2 = wg - 64;
    const int j  = w2 * 8 + wave;         // owned h2 index
    const int r  = g * HDIM + j;
    float wb[64];                          // row = [W_ih2[r,0:512] | W_hh2[r,0:512]], chunk-rotated
#pragma unroll
    for (int c = 0; c < 16; ++c) {
#pragma unroll
      for (int i = 0; i < 4; ++i) {
        int er = s * 64 + ((c + s) & 15) * 4 + i;   // 0..1023
        wb[c * 4 + i] = (er < HDIM) ? W_ih2[(size_t)r * HDIM + er]
                                    : W_hh2[(size_t)r * HDIM + (er - HDIM)];
      }
    }
#pragma unroll
    for (int m = 0; m < 64; ++m) asm volatile("" : "+v"(wb[m]));
    const float bsel = b_ih2[r] + b_hh2[r];
    float cst = 0.f;

    for (int m = 0; m < T_LEN; ++m) {
      const int buf = m & 1;
      const unsigned ex1 = (unsigned)m;       // h1(m) from the ring
      const unsigned ex2 = (unsigned)(m - 1); // h2(m-1), parity (m-1)&1 == (m+1)&1

      unsigned long long a = 0, b = 0;
      bool ok1 = false, ok2 = false;
      do {
        if (!ok1) {
          a = __hip_atomic_load(&g_r1[m % RD][tid],
                                __ATOMIC_RELAXED, __HIP_MEMORY_SCOPE_AGENT);
          ok1 = ((unsigned)(a >> 32) == ex1);
        }
        if (!ok2) {
          b = __hip_atomic_load(&g_r2[(m + 1) & 1][tid],
                                __ATOMIC_RELAXED, __HIP_MEMORY_SCOPE_AGENT);
          ok2 = ((unsigned)(b >> 32) == ex2);
        }
      } while ((!ok1 || !ok2) && --bud > 0);

      vec[buf][tid]        = __uint_as_float((unsigned)a);  // h1(m)
      vec[buf][HDIM + tid] = __uint_as_float((unsigned)b);  // h2(m-1)
      __syncthreads();
      // all threads' h1(m) ring loads are complete -> release the ring slot
      if (tid == 0)
        __hip_atomic_store(&g_prog[w2], (long long)m,
                           __ATOMIC_RELAXED, __HIP_MEMORY_SCOPE_AGENT);

      float acc = 0.f;
#pragma unroll
      for (int c = 0; c < 16; ++c) {
        const int off = s * 64 + ((c + s) & 15) * 4;   // contiguous [h1|h2], no gap
        const float4 hv = *reinterpret_cast<const float4*>(&vec[buf][off]);
        acc = fmaf(wb[c * 4 + 0], hv.x, acc);
        acc = fmaf(wb[c * 4 + 1], hv.y, acc);
        acc = fmaf(wb[c * 4 + 2], hv.z, acc);
        acc = fmaf(wb[c * 4 + 3], hv.w, acc);
      }
      acc += __shfl_xor(acc, 8, 16);
      acc += __shfl_xor(acc, 4, 16);
      acc += __shfl_xor(acc, 2, 16);
      acc += __shfl_xor(acc, 1, 16);
      const float xs  = acc + bsel;
      const float xin = (g == 2) ? 2.f * xs : xs;
      const float sgm = 1.f / (1.f + expf(-xin));
      const float act = (g == 2) ? 2.f * sgm - 1.f : sgm;
      const float ai = __shfl(act, 0, 64);
      const float af = __shfl(act, 16, 64);
      const float ag = __shfl(act, 32, 64);
      const float ao = __shfl(act, 48, 64);
      cst = af * cst + ai * ag;
      const float tc = 2.f / (1.f + expf(-2.f * cst)) - 1.f;   // tanh
      const float hv2 = ao * tc;
      if (lane == 0)
        __hip_atomic_store(&g_r2[m & 1][j], pack(hv2, m),
                           __ATOMIC_RELAXED, __HIP_MEMORY_SCOPE_AGENT);
    }

    // ---- final output: out = W_out . h2(T-1) + b_out  (tag T-1, parity 1) ----
    if (w2 == 0 && wave == 0) {
      float acc = 0.f;
      int bud2 = 1 << 24;
#pragma unroll
      for (int e = 0; e < HDIM / 64; ++e) {
        const int idx = lane + e * 64;
        unsigned long long u;
        do {
          u = __hip_atomic_load(&g_r2[1][idx],
                                __ATOMIC_RELAXED, __HIP_MEMORY_SCOPE_AGENT);
        } while ((unsigned)(u >> 32) != (unsigned)(T_LEN - 1) && --bud2 > 0);
        acc = fmaf(W_out[idx], __uint_as_float((unsigned)u), acc);
      }
      acc += __shfl_xor(acc, 32, 64);
      acc += __shfl_xor(acc, 16, 64);
      acc += __shfl_xor(acc, 8, 64);
      acc += __shfl_xor(acc, 4, 64);
      acc += __shfl_xor(acc, 2, 64);
      acc += __shfl_xor(acc, 1, 64);
      if (lane == 0) out[0] = acc + b_out[0];
    }
  }
}

extern "C" void kernel_launch(void* const* d_in, const int* in_sizes, int n_in,
                              void* d_out, int out_size, void* d_ws, size_t ws_size,
                              hipStream_t stream) {
  const float* x_seq = (const float*)d_in[0];
  const float* W_ih1 = (const float*)d_in[1];
  const float* W_hh1 = (const float*)d_in[2];
  const float* b_ih1 = (const float*)d_in[3];
  const float* b_hh1 = (const float*)d_in[4];
  const float* W_ih2 = (const float*)d_in[5];
  const float* W_hh2 = (const float*)d_in[6];
  const float* b_ih2 = (const float*)d_in[7];
  const float* b_hh2 = (const float*)d_in[8];
  const float* W_out = (const float*)d_in[9];
  const float* b_out = (const float*)d_in[10];
  float* out = (float*)d_out;

  hipLaunchKernelGGL(lstm_init, dim3(1), dim3(256), 0, stream);
  hipLaunchKernelGGL(lstm_main, dim3(NWG), dim3(NTHR), 0, stream,
                     x_seq, W_ih1, W_hh1, b_ih1, b_hh1,
                     W_ih2, W_hh2, b_ih2, b_hh2, W_out, b_out, out);
}

// Round 13
// 126227.649 us; speedup vs baseline: 2.0128x; 1.4496x over previous
//
#include <hip/hip_runtime.h>

#define IDIM  64
#define HDIM  512
#define T_LEN 65536
#define NWG   128
#define NTHR  512

// Tagged hidden state: high 32 bits = tick tag, low 32 bits = float payload.
// The tag check doubles as the device-wide barrier (data+signal in one 8B word).
// Byte-identical protocol to the verified R5 kernel (129 ms, absmax 0.0).
__device__ unsigned long long g_h1[2][HDIM];
__device__ unsigned long long g_h2[2][HDIM];

__device__ __forceinline__ unsigned long long pack(float v, int k) {
  return ((unsigned long long)(unsigned)k << 32) | (unsigned long long)__float_as_uint(v);
}

__global__ void lstm_init() {
  int t = threadIdx.x;
  for (int e = t; e < HDIM; e += blockDim.x) {
    g_h1[0][e] = 0xFFFFFFFF00000000ull;  // tag=-1, val=0
    g_h1[1][e] = 0xFFFFFFFF00000000ull;  // read at tick 0 (expect -1)
    g_h2[0][e] = 0xFFFFFFFF00000000ull;  // read at tick 0 (expect -1)
    g_h2[1][e] = 0x0000000000000000ull;  // tag=0,val=0: h2(-1), read at tick 1
  }
}

__global__ __launch_bounds__(NTHR)
__attribute__((amdgpu_waves_per_eu(2, 2)))   // the ONLY shape that keeps w[64] resident (VGPR 88)
void lstm_main(
    const float* __restrict__ x_seq,
    const float* __restrict__ W_ih1, const float* __restrict__ W_hh1,
    const float* __restrict__ b_ih1, const float* __restrict__ b_hh1,
    const float* __restrict__ W_ih2, const float* __restrict__ W_hh2,
    const float* __restrict__ b_ih2, const float* __restrict__ b_hh2,
    const float* __restrict__ W_out, const float* __restrict__ b_out,
    float* __restrict__ out)
{
  const int wg   = blockIdx.x;
  const int tid  = threadIdx.x;
  const int wave = tid >> 6;      // 0..7
  const int role = wave >> 2;     // 0 = layer1, 1 = layer2
  const int lane = tid & 63;
  const int g    = lane >> 4;     // gate 0..3 (i,f,g,o)
  const int s    = lane & 15;     // strip 0..15
  const int j    = wg * 4 + (wave & 3);   // owned hidden index for this (j,layer) wave
  const int r    = g * HDIM + j;          // gate row in [0,2048)

  // ---- weights -> VGPRs: ONE array, role-dependent contents (max 64 live floats) ----
  float w[64];
  if (role == 0) {
    // layer1 row = [W_hh1[r,0:512] | W_ih1[r,0:64]]; lane covers e = s*36 .. s*36+35
#pragma unroll
    for (int m = 0; m < 36; ++m) {
      int e = s * 36 + m;
      w[m] = (e < HDIM) ? W_hh1[(size_t)r * HDIM + e]
                        : W_ih1[(size_t)r * IDIM + (e - HDIM)];
    }
#pragma unroll
    for (int m = 0; m < 36; ++m) asm volatile("" : "+v"(w[m]));  // forbid remat
  } else {
    // layer2 row = [W_ih2[r,0:512] | W_hh2[r,0:512]]; lane covers e = s*64 .. s*64+63,
    // chunk-rotated by s to avoid LDS bank conflicts on the stride-256B read pattern.
#pragma unroll
    for (int c = 0; c < 16; ++c) {
#pragma unroll
      for (int i = 0; i < 4; ++i) {
        int er = s * 64 + ((c + s) & 15) * 4 + i;   // 0..1023
        w[c * 4 + i] = (er < HDIM) ? W_ih2[(size_t)r * HDIM + er]
                                   : W_hh2[(size_t)r * HDIM + (er - HDIM)];
      }
    }
#pragma unroll
    for (int m = 0; m < 64; ++m) asm volatile("" : "+v"(w[m]));  // forbid remat
  }
  const float bsel = (role == 0) ? (b_ih1[r] + b_hh1[r]) : (b_ih2[r] + b_hh2[r]);

  float cst = 0.f;                 // cell state for owned (j, layer)
  int bud = 1 << 22;               // GLOBAL spin budget: fail fast, not per-tick

  __shared__ __align__(16) float vec[2][HDIM + IDIM + HDIM]; // [h1_prev | x_k | h2_prev] x2

  for (int k = 0; k <= T_LEN; ++k) {
    const unsigned expect = (unsigned)(k - 1);
    const int p1  = (k + 1) & 1;  // h1 tag k-1 parity
    const int p2  = k & 1;        // h2 tag k-1 parity
    const int buf = k & 1;

    // x load issued before the poll so its latency hides under it
    float xv = 0.f;
    if (tid < IDIM && k < T_LEN) xv = x_seq[(size_t)k * IDIM + tid];

    // ---- per-thread spin; paced retry: sleep ~256cy on miss so the MALL
    //      queue drains instead of being saturated by immediate re-issues ----
    unsigned long long a = 0, b = 0;
    bool ok1 = false, ok2 = false;
    do {
      if (!ok1) {
        a = __hip_atomic_load(&g_h1[p1][tid], __ATOMIC_RELAXED, __HIP_MEMORY_SCOPE_AGENT);
        ok1 = ((unsigned)(a >> 32) == expect);
      }
      if (!ok2) {
        b = __hip_atomic_load(&g_h2[p2][tid], __ATOMIC_RELAXED, __HIP_MEMORY_SCOPE_AGENT);
        ok2 = ((unsigned)(b >> 32) == expect);
      }
      if (ok1 && ok2) break;
      __builtin_amdgcn_s_sleep(4);   // paced retry (the single change vs R5)
    } while (--bud > 0);

    vec[buf][tid] = __uint_as_float((unsigned)a);
    vec[buf][HDIM + IDIM + tid] = __uint_as_float((unsigned)b);
    if (tid < IDIM) vec[buf][HDIM + tid] = xv;
    __syncthreads();   // only barrier per tick; vec is double-buffered

    // ---- compute: role 0 = layer1 step k; role 1 = layer2 step k-1 ----
    const bool active = (role == 0) ? (k < T_LEN) : (k > 0);
    if (active) {
      float acc = 0.f;
      if (role == 0) {
#pragma unroll
        for (int mc = 0; mc < 9; ++mc) {
          const float4 hv = *reinterpret_cast<const float4*>(&vec[buf][s * 36 + mc * 4]);
          acc = fmaf(w[mc * 4 + 0], hv.x, acc);
          acc = fmaf(w[mc * 4 + 1], hv.y, acc);
          acc = fmaf(w[mc * 4 + 2], hv.z, acc);
          acc = fmaf(w[mc * 4 + 3], hv.w, acc);
        }
      } else {
        const int vb = (s < 8) ? 0 : IDIM;  // skip the x-gap for the h2 half
#pragma unroll
        for (int c = 0; c < 16; ++c) {
          const int off = s * 64 + ((c + s) & 15) * 4 + vb;
          const float4 hv = *reinterpret_cast<const float4*>(&vec[buf][off]);
          acc = fmaf(w[c * 4 + 0], hv.x, acc);
          acc = fmaf(w[c * 4 + 1], hv.y, acc);
          acc = fmaf(w[c * 4 + 2], hv.z, acc);
          acc = fmaf(w[c * 4 + 3], hv.w, acc);
        }
      }
      acc += __shfl_xor(acc, 8, 16);
      acc += __shfl_xor(acc, 4, 16);
      acc += __shfl_xor(acc, 2, 16);
      acc += __shfl_xor(acc, 1, 16);

      // per-group activation (tanh via 2*sigmoid(2x)-1), broadcast activated gates
      const float xs  = acc + bsel;
      const float xin = (g == 2) ? 2.f * xs : xs;
      const float sgm = 1.f / (1.f + expf(-xin));
      const float act = (g == 2) ? 2.f * sgm - 1.f : sgm;
      const float ai = __shfl(act, 0, 64);
      const float af = __shfl(act, 16, 64);
      const float ag = __shfl(act, 32, 64);
      const float ao = __shfl(act, 48, 64);
      cst = af * cst + ai * ag;
      const float tc = 2.f / (1.f + expf(-2.f * cst)) - 1.f;   // tanh(cst)
      const float hv = ao * tc;
      if (lane == 0) {
        if (role == 0)
          __hip_atomic_store(&g_h1[k & 1][j], pack(hv, k),
                             __ATOMIC_RELAXED, __HIP_MEMORY_SCOPE_AGENT);
        else
          __hip_atomic_store(&g_h2[(k + 1) & 1][j], pack(hv, k),
                             __ATOMIC_RELAXED, __HIP_MEMORY_SCOPE_AGENT);
      }
    }
    // no trailing barrier: double-buffered vec + per-tick barrier keep WAR safe
  }

  // ---- final output: out = W_out . h2(T-1) + b_out  (tag T_LEN, parity 1) ----
  if (wg == 0 && wave == 0) {
    float acc = 0.f;
    int bud2 = 1 << 22;
#pragma unroll
    for (int e = 0; e < HDIM / 64; ++e) {
      const int idx = lane + e * 64;
      unsigned long long u;
      do {
        u = __hip_atomic_load(&g_h2[1][idx], __ATOMIC_RELAXED, __HIP_MEMORY_SCOPE_AGENT);
      } while ((unsigned)(u >> 32) != (unsigned)T_LEN && --bud2 > 0);
      acc = fmaf(W_out[idx], __uint_as_float((unsigned)u), acc);
    }
    acc += __shfl_xor(acc, 32, 64);
    acc += __shfl_xor(acc, 16, 64);
    acc += __shfl_xor(acc, 8, 64);
    acc += __shfl_xor(acc, 4, 64);
    acc += __shfl_xor(acc, 2, 64);
    acc += __shfl_xor(acc, 1, 64);
    if (lane == 0) out[0] = acc + b_out[0];
  }
}

extern "C" void kernel_launch(void* const* d_in, const int* in_sizes, int n_in,
                              void* d_out, int out_size, void* d_ws, size_t ws_size,
                              hipStream_t stream) {
  const float* x_seq = (const float*)d_in[0];
  const float* W_ih1 = (const float*)d_in[1];
  const float* W_hh1 = (const float*)d_in[2];
  const float* b_ih1 = (const float*)d_in[3];
  const float* b_hh1 = (const float*)d_in[4];
  const float* W_ih2 = (const float*)d_in[5];
  const float* W_hh2 = (const float*)d_in[6];
  const float* b_ih2 = (const float*)d_in[7];
  const float* b_hh2 = (const float*)d_in[8];
  const float* W_out = (const float*)d_in[9];
  const float* b_out = (const float*)d_in[10];
  float* out = (float*)d_out;

  hipLaunchKernelGGL(lstm_init, dim3(1), dim3(256), 0, stream);
  hipLaunchKernelGGL(lstm_main, dim3(NWG), dim3(NTHR), 0, stream,
                     x_seq, W_ih1, W_hh1, b_ih1, b_hh1,
                     W_ih2, W_hh2, b_ih2, b_hh2, W_out, b_out, out);
}

// Round 14
// 118337.524 us; speedup vs baseline: 2.1470x; 1.0667x over previous
//
#include <hip/hip_runtime.h>

#define IDIM  64
#define HDIM  512
#define T_LEN 65536
#define NWG   128
#define NTHR  512

// Tagged hidden state: high 32 bits = tick tag, low 32 bits = float payload.
// The tag check doubles as the device-wide barrier (data+signal in one 8B word).
// Protocol byte-identical to R5/R13 (verified absmax 0.0).
__device__ unsigned long long g_h1[2][HDIM];
__device__ unsigned long long g_h2[2][HDIM];

__device__ __forceinline__ unsigned long long pack(float v, int k) {
  return ((unsigned long long)(unsigned)k << 32) | (unsigned long long)__float_as_uint(v);
}

__global__ void lstm_init() {
  int t = threadIdx.x;
  for (int e = t; e < HDIM; e += blockDim.x) {
    g_h1[0][e] = 0xFFFFFFFF00000000ull;  // tag=-1, val=0
    g_h1[1][e] = 0xFFFFFFFF00000000ull;  // read at tick 0 (expect -1)
    g_h2[0][e] = 0xFFFFFFFF00000000ull;  // read at tick 0 (expect -1)
    g_h2[1][e] = 0x0000000000000000ull;  // tag=0,val=0: h2(-1), read at tick 1
  }
}

__global__ __launch_bounds__(NTHR)
__attribute__((amdgpu_waves_per_eu(2, 2)))   // the ONLY shape that keeps w[64] resident (VGPR 88)
void lstm_main(
    const float* __restrict__ x_seq,
    const float* __restrict__ W_ih1, const float* __restrict__ W_hh1,
    const float* __restrict__ b_ih1, const float* __restrict__ b_hh1,
    const float* __restrict__ W_ih2, const float* __restrict__ W_hh2,
    const float* __restrict__ b_ih2, const float* __restrict__ b_hh2,
    const float* __restrict__ W_out, const float* __restrict__ b_out,
    float* __restrict__ out)
{
  const int wg   = blockIdx.x;
  const int tid  = threadIdx.x;
  const int wave = tid >> 6;      // 0..7
  const int role = wave >> 2;     // 0 = layer1, 1 = layer2
  const int lane = tid & 63;
  const int g    = lane >> 4;     // gate 0..3 (i,f,g,o)
  const int s    = lane & 15;     // strip 0..15
  const int j    = wg * 4 + (wave & 3);   // owned hidden index for this (j,layer) wave
  const int r    = g * HDIM + j;          // gate row in [0,2048)

  // ---- weights -> VGPRs: ONE array, role-dependent contents (max 64 live floats) ----
  float w[64];
  if (role == 0) {
    // layer1 row = [W_hh1[r,0:512] | W_ih1[r,0:64]]; lane covers e = s*36 .. s*36+35
#pragma unroll
    for (int m = 0; m < 36; ++m) {
      int e = s * 36 + m;
      w[m] = (e < HDIM) ? W_hh1[(size_t)r * HDIM + e]
                        : W_ih1[(size_t)r * IDIM + (e - HDIM)];
    }
#pragma unroll
    for (int m = 0; m < 36; ++m) asm volatile("" : "+v"(w[m]));  // forbid remat
  } else {
    // layer2 row = [W_ih2[r,0:512] | W_hh2[r,0:512]]; lane covers e = s*64 .. s*64+63,
    // chunk-rotated by s to avoid LDS bank conflicts on the stride-256B read pattern.
#pragma unroll
    for (int c = 0; c < 16; ++c) {
#pragma unroll
      for (int i = 0; i < 4; ++i) {
        int er = s * 64 + ((c + s) & 15) * 4 + i;   // 0..1023
        w[c * 4 + i] = (er < HDIM) ? W_ih2[(size_t)r * HDIM + er]
                                   : W_hh2[(size_t)r * HDIM + (er - HDIM)];
      }
    }
#pragma unroll
    for (int m = 0; m < 64; ++m) asm volatile("" : "+v"(w[m]));  // forbid remat
  }
  const float bsel = (role == 0) ? (b_ih1[r] + b_hh1[r]) : (b_ih2[r] + b_hh2[r]);

  float cst = 0.f;                 // cell state for owned (j, layer)
  int bud = 1 << 22;               // GLOBAL spin budget: fail fast, not per-tick

  __shared__ __align__(16) float vec[2][HDIM + IDIM + HDIM]; // [h1_prev | x_k | h2_prev] x2

  for (int k = 0; k <= T_LEN; ++k) {
    const unsigned expect = (unsigned)(k - 1);
    const int p1  = (k + 1) & 1;  // h1 tag k-1 parity
    const int p2  = k & 1;        // h2 tag k-1 parity
    const int buf = k & 1;

    // x load issued before the poll so its latency hides under it
    float xv = 0.f;
    if (tid < IDIM && k < T_LEN) xv = x_seq[(size_t)k * IDIM + tid];

    // ---- per-thread spin; paced retry (sleep ~128cy) ----
    unsigned long long a = 0, b = 0;
    bool ok1 = false, ok2 = false;
    do {
      if (!ok1) {
        a = __hip_atomic_load(&g_h1[p1][tid], __ATOMIC_RELAXED, __HIP_MEMORY_SCOPE_AGENT);
        ok1 = ((unsigned)(a >> 32) == expect);
      }
      if (!ok2) {
        b = __hip_atomic_load(&g_h2[p2][tid], __ATOMIC_RELAXED, __HIP_MEMORY_SCOPE_AGENT);
        ok2 = ((unsigned)(b >> 32) == expect);
      }
      if (ok1 && ok2) break;
      __builtin_amdgcn_s_sleep(2);
    } while (--bud > 0);

    vec[buf][tid] = __uint_as_float((unsigned)a);
    vec[buf][HDIM + IDIM + tid] = __uint_as_float((unsigned)b);
    if (tid < IDIM) vec[buf][HDIM + tid] = xv;
    __syncthreads();   // only barrier per tick; vec is double-buffered

    // ---- compute: role 0 = layer1 step k; role 1 = layer2 step k-1 ----
    const bool active = (role == 0) ? (k < T_LEN) : (k > 0);
    if (active) {
      // 4 independent component accumulators: dep-chain 16 deep instead of 64
      float ax = 0.f, ay = 0.f, az = 0.f, aw = 0.f;
      if (role == 0) {
#pragma unroll
        for (int mc = 0; mc < 9; ++mc) {
          const float4 hv = *reinterpret_cast<const float4*>(&vec[buf][s * 36 + mc * 4]);
          ax = fmaf(w[mc * 4 + 0], hv.x, ax);
          ay = fmaf(w[mc * 4 + 1], hv.y, ay);
          az = fmaf(w[mc * 4 + 2], hv.z, az);
          aw = fmaf(w[mc * 4 + 3], hv.w, aw);
        }
      } else {
        const int vb = (s < 8) ? 0 : IDIM;  // skip the x-gap for the h2 half
#pragma unroll
        for (int c = 0; c < 16; ++c) {
          const int off = s * 64 + ((c + s) & 15) * 4 + vb;
          const float4 hv = *reinterpret_cast<const float4*>(&vec[buf][off]);
          ax = fmaf(w[c * 4 + 0], hv.x, ax);
          ay = fmaf(w[c * 4 + 1], hv.y, ay);
          az = fmaf(w[c * 4 + 2], hv.z, az);
          aw = fmaf(w[c * 4 + 3], hv.w, aw);
        }
      }
      float acc = (ax + ay) + (az + aw);
      acc += __shfl_xor(acc, 8, 16);
      acc += __shfl_xor(acc, 4, 16);
      acc += __shfl_xor(acc, 2, 16);
      acc += __shfl_xor(acc, 1, 16);

      // per-group activation (tanh via 2*sigmoid(2x)-1), fast native exp
      const float xs  = acc + bsel;
      const float xin = (g == 2) ? 2.f * xs : xs;
      const float sgm = 1.f / (1.f + __expf(-xin));
      const float act = (g == 2) ? 2.f * sgm - 1.f : sgm;
      const float ai = __shfl(act, 0, 64);
      const float af = __shfl(act, 16, 64);
      const float ag = __shfl(act, 32, 64);
      const float ao = __shfl(act, 48, 64);
      cst = af * cst + ai * ag;
      const float tc = 2.f / (1.f + __expf(-2.f * cst)) - 1.f;   // tanh(cst)
      const float hv = ao * tc;
      if (lane == 0) {
        if (role == 0)
          __hip_atomic_store(&g_h1[k & 1][j], pack(hv, k),
                             __ATOMIC_RELAXED, __HIP_MEMORY_SCOPE_AGENT);
        else
          __hip_atomic_store(&g_h2[(k + 1) & 1][j], pack(hv, k),
                             __ATOMIC_RELAXED, __HIP_MEMORY_SCOPE_AGENT);
      }
    }
    // no trailing barrier: double-buffered vec + per-tick barrier keep WAR safe
  }

  // ---- final output: out = W_out . h2(T-1) + b_out  (tag T_LEN, parity 1) ----
  if (wg == 0 && wave == 0) {
    float acc = 0.f;
    int bud2 = 1 << 22;
#pragma unroll
    for (int e = 0; e < HDIM / 64; ++e) {
      const int idx = lane + e * 64;
      unsigned long long u;
      do {
        u = __hip_atomic_load(&g_h2[1][idx], __ATOMIC_RELAXED, __HIP_MEMORY_SCOPE_AGENT);
      } while ((unsigned)(u >> 32) != (unsigned)T_LEN && --bud2 > 0);
      acc = fmaf(W_out[idx], __uint_as_float((unsigned)u), acc);
    }
    acc += __shfl_xor(acc, 32, 64);
    acc += __shfl_xor(acc, 16, 64);
    acc += __shfl_xor(acc, 8, 64);
    acc += __shfl_xor(acc, 4, 64);
    acc += __shfl_xor(acc, 2, 64);
    acc += __shfl_xor(acc, 1, 64);
    if (lane == 0) out[0] = acc + b_out[0];
  }
}

extern "C" void kernel_launch(void* const* d_in, const int* in_sizes, int n_in,
                              void* d_out, int out_size, void* d_ws, size_t ws_size,
                              hipStream_t stream) {
  const float* x_seq = (const float*)d_in[0];
  const float* W_ih1 = (const float*)d_in[1];
  const float* W_hh1 = (const float*)d_in[2];
  const float* b_ih1 = (const float*)d_in[3];
  const float* b_hh1 = (const float*)d_in[4];
  const float* W_ih2 = (const float*)d_in[5];
  const float* W_hh2 = (const float*)d_in[6];
  const float* b_ih2 = (const float*)d_in[7];
  const float* b_hh2 = (const float*)d_in[8];
  const float* W_out = (const float*)d_in[9];
  const float* b_out = (const float*)d_in[10];
  float* out = (float*)d_out;

  hipLaunchKernelGGL(lstm_init, dim3(1), dim3(256), 0, stream);
  hipLaunchKernelGGL(lstm_main, dim3(NWG), dim3(NTHR), 0, stream,
                     x_seq, W_ih1, W_hh1, b_ih1, b_hh1,
                     W_ih2, W_hh2, b_ih2, b_hh2, W_out, b_out, out);
}

// Round 16
// 118259.497 us; speedup vs baseline: 2.1485x; 1.0007x over previous
//
#include <hip/hip_runtime.h>

#define IDIM  64
#define HDIM  512
#define T_LEN 65536
#define NWG   128
#define NTHR  512

// Merged tagged hidden state (R11-verified layout/init): slots 0..511 = h1,
// 512..1023 = h2. Record: hi32 = tick tag, lo32 = float payload.
// Producers at tick k (both layers) write parity k&1; consumers read (k+1)&1.
// Thread t polls the ADJACENT pair {2t, 2t+1}: same cache line, same producer
// WG, correlated arrival -> per-thread detect ~1 line-RTT (vs 2 independent).
__device__ unsigned long long g_hh[2][2 * HDIM];

__device__ __forceinline__ unsigned long long pack(float v, int k) {
  return ((unsigned long long)(unsigned)k << 32) | (unsigned long long)__float_as_uint(v);
}

__global__ void lstm_init() {
  int t = threadIdx.x;
  for (int e = t; e < HDIM; e += blockDim.x) {
    g_hh[1][e]        = 0xFFFFFFFF00000000ull; // h1 tag=-1 val=0 : read at tick 0
    g_hh[0][e]        = 0xFFFFFFFE00000000ull; // h1 never-match : overwritten at tick 0
    g_hh[1][HDIM + e] = 0xFFFFFFFF00000000ull; // h2 tag=-1 val=0 : read at tick 0
    g_hh[0][HDIM + e] = 0x0000000000000000ull; // h2 tag=0 val=0 : h2(-1), read at tick 1
  }
}

__global__ __launch_bounds__(NTHR)
__attribute__((amdgpu_waves_per_eu(2, 2)))   // the ONLY shape that keeps w[64] resident (VGPR 88)
void lstm_main(
    const float* __restrict__ x_seq,
    const float* __restrict__ W_ih1, const float* __restrict__ W_hh1,
    const float* __restrict__ b_ih1, const float* __restrict__ b_hh1,
    const float* __restrict__ W_ih2, const float* __restrict__ W_hh2,
    const float* __restrict__ b_ih2, const float* __restrict__ b_hh2,
    const float* __restrict__ W_out, const float* __restrict__ b_out,
    float* __restrict__ out)
{
  const int wg   = blockIdx.x;
  const int tid  = threadIdx.x;
  const int wave = tid >> 6;      // 0..7
  const int role = wave >> 2;     // 0 = layer1, 1 = layer2
  const int lane = tid & 63;
  const int g    = lane >> 4;     // gate 0..3 (i,f,g,o)
  const int s    = lane & 15;     // strip 0..15
  const int j    = wg * 4 + (wave & 3);   // owned hidden index for this (j,layer) wave
  const int r    = g * HDIM + j;          // gate row in [0,2048)

  // ---- weights -> VGPRs: ONE array, role-dependent contents (max 64 live floats) ----
  float w[64];
  if (role == 0) {
    // layer1 row = [W_hh1[r,0:512] | W_ih1[r,0:64]]; lane covers e = s*36 .. s*36+35
#pragma unroll
    for (int m = 0; m < 36; ++m) {
      int e = s * 36 + m;
      w[m] = (e < HDIM) ? W_hh1[(size_t)r * HDIM + e]
                        : W_ih1[(size_t)r * IDIM + (e - HDIM)];
    }
#pragma unroll
    for (int m = 0; m < 36; ++m) asm volatile("" : "+v"(w[m]));  // forbid remat
  } else {
    // layer2 row = [W_ih2[r,0:512] | W_hh2[r,0:512]]; lane covers e = s*64 .. s*64+63,
    // chunk-rotated by s to avoid LDS bank conflicts on the stride-256B read pattern.
#pragma unroll
    for (int c = 0; c < 16; ++c) {
#pragma unroll
      for (int i = 0; i < 4; ++i) {
        int er = s * 64 + ((c + s) & 15) * 4 + i;   // 0..1023
        w[c * 4 + i] = (er < HDIM) ? W_ih2[(size_t)r * HDIM + er]
                                   : W_hh2[(size_t)r * HDIM + (er - HDIM)];
      }
    }
#pragma unroll
    for (int m = 0; m < 64; ++m) asm volatile("" : "+v"(w[m]));  // forbid remat
  }
  const float bsel = (role == 0) ? (b_ih1[r] + b_hh1[r]) : (b_ih2[r] + b_hh2[r]);

  float cst = 0.f;                 // cell state for owned (j, layer)
  int bud = 1 << 22;               // GLOBAL spin budget: fail fast, not per-tick

  __shared__ __align__(16) float vec[2][HDIM + IDIM + HDIM]; // [h1_prev | x_k | h2_prev] x2
  const int s0 = tid * 2;          // this thread's adjacent slot pair

  for (int k = 0; k <= T_LEN; ++k) {
    const unsigned expect = (unsigned)(k - 1);
    const int pb  = (k + 1) & 1;  // parity holding tag k-1
    const int buf = k & 1;

    // x load issued before the poll so its latency hides under it
    float xv = 0.f;
    if (tid < IDIM && k < T_LEN) xv = x_seq[(size_t)k * IDIM + tid];

    // ---- per-thread spin on one SAME-LINE slot pair; paced retry ----
    unsigned long long a = 0, b = 0;
    bool ok1 = false, ok2 = false;
    do {
      if (!ok1) {
        a = __hip_atomic_load(&g_hh[pb][s0], __ATOMIC_RELAXED, __HIP_MEMORY_SCOPE_AGENT);
        ok1 = ((unsigned)(a >> 32) == expect);
      }
      if (!ok2) {
        b = __hip_atomic_load(&g_hh[pb][s0 + 1], __ATOMIC_RELAXED, __HIP_MEMORY_SCOPE_AGENT);
        ok2 = ((unsigned)(b >> 32) == expect);
      }
      if (ok1 && ok2) break;
      __builtin_amdgcn_s_sleep(2);
    } while (--bud > 0);

    const int d0 = (s0 < HDIM) ? s0 : s0 + IDIM;   // h2 half sits after the x gap
    vec[buf][d0]     = __uint_as_float((unsigned)a);
    vec[buf][d0 + 1] = __uint_as_float((unsigned)b);
    if (tid < IDIM) vec[buf][HDIM + tid] = xv;
    __syncthreads();   // only barrier per tick; vec is double-buffered

    // ---- compute: role 0 = layer1 step k; role 1 = layer2 step k-1 ----
    const bool active = (role == 0) ? (k < T_LEN) : (k > 0);
    if (active) {
      // 4 independent component accumulators: dep-chain 16 deep instead of 64
      float ax = 0.f, ay = 0.f, az = 0.f, aw = 0.f;
      if (role == 0) {
#pragma unroll
        for (int mc = 0; mc < 9; ++mc) {
          const float4 hv = *reinterpret_cast<const float4*>(&vec[buf][s * 36 + mc * 4]);
          ax = fmaf(w[mc * 4 + 0], hv.x, ax);
          ay = fmaf(w[mc * 4 + 1], hv.y, ay);
          az = fmaf(w[mc * 4 + 2], hv.z, az);
          aw = fmaf(w[mc * 4 + 3], hv.w, aw);
        }
      } else {
        const int vb = (s < 8) ? 0 : IDIM;  // skip the x-gap for the h2 half
#pragma unroll
        for (int c = 0; c < 16; ++c) {
          const int off = s * 64 + ((c + s) & 15) * 4 + vb;
          const float4 hv = *reinterpret_cast<const float4*>(&vec[buf][off]);
          ax = fmaf(w[c * 4 + 0], hv.x, ax);
          ay = fmaf(w[c * 4 + 1], hv.y, ay);
          az = fmaf(w[c * 4 + 2], hv.z, az);
          aw = fmaf(w[c * 4 + 3], hv.w, aw);
        }
      }
      float acc = (ax + ay) + (az + aw);
      acc += __shfl_xor(acc, 8, 16);
      acc += __shfl_xor(acc, 4, 16);
      acc += __shfl_xor(acc, 2, 16);
      acc += __shfl_xor(acc, 1, 16);

      // per-group activation (tanh via 2*sigmoid(2x)-1), fast native exp
      const float xs  = acc + bsel;
      const float xin = (g == 2) ? 2.f * xs : xs;
      const float sgm = 1.f / (1.f + __expf(-xin));
      const float act = (g == 2) ? 2.f * sgm - 1.f : sgm;
      const float ai = __shfl(act, 0, 64);
      const float af = __shfl(act, 16, 64);
      const float ag = __shfl(act, 32, 64);
      const float ao = __shfl(act, 48, 64);
      cst = af * cst + ai * ag;
      const float tc = 2.f / (1.f + __expf(-2.f * cst)) - 1.f;   // tanh(cst)
      const float hv = ao * tc;
      if (lane == 0) {
        const int vidx = (role == 0) ? j : (HDIM + j);
        __hip_atomic_store(&g_hh[k & 1][vidx], pack(hv, k),
                           __ATOMIC_RELAXED, __HIP_MEMORY_SCOPE_AGENT);
      }
    }
    // no trailing barrier: double-buffered vec + per-tick barrier keep WAR safe
  }

  // ---- final output: out = W_out . h2(T-1) + b_out  (tag T_LEN, parity 0) ----
  if (wg == 0 && wave == 0) {
    float acc = 0.f;
    int bud2 = 1 << 22;
#pragma unroll
    for (int e = 0; e < HDIM / 64; ++e) {
      const int idx = lane + e * 64;
      unsigned long long u;
      do {
        u = __hip_atomic_load(&g_hh[0][HDIM + idx], __ATOMIC_RELAXED, __HIP_MEMORY_SCOPE_AGENT);
      } while ((unsigned)(u >> 32) != (unsigned)T_LEN && --bud2 > 0);
      acc = fmaf(W_out[idx], __uint_as_float((unsigned)u), acc);
    }
    acc += __shfl_xor(acc, 32, 64);
    acc += __shfl_xor(acc, 16, 64);
    acc += __shfl_xor(acc, 8, 64);
    acc += __shfl_xor(acc, 4, 64);
    acc += __shfl_xor(acc, 2, 64);
    acc += __shfl_xor(acc, 1, 64);
    if (lane == 0) out[0] = acc + b_out[0];
  }
}

extern "C" void kernel_launch(void* const* d_in, const int* in_sizes, int n_in,
                              void* d_out, int out_size, void* d_ws, size_t ws_size,
                              hipStream_t stream) {
  const float* x_seq = (const float*)d_in[0];
  const float* W_ih1 = (const float*)d_in[1];
  const float* W_hh1 = (const float*)d_in[2];
  const float* b_ih1 = (const float*)d_in[3];
  const float* b_hh1 = (const float*)d_in[4];
  const float* W_ih2 = (const float*)d_in[5];
  const float* W_hh2 = (const float*)d_in[6];
  const float* b_ih2 = (const float*)d_in[7];
  const float* b_hh2 = (const float*)d_in[8];
  const float* W_out = (const float*)d_in[9];
  const float* b_out = (const float*)d_in[10];
  float* out = (float*)d_out;

  hipLaunchKernelGGL(lstm_init, dim3(1), dim3(256), 0, stream);
  hipLaunchKernelGGL(lstm_main, dim3(NWG), dim3(NTHR), 0, stream,
                     x_seq, W_ih1, W_hh1, b_ih1, b_hh1,
                     W_ih2, W_hh2, b_ih2, b_hh2, W_out, b_out, out);
}